// Round 11
// baseline (98.102 us; speedup 1.0000x reference)
//
#include <hip/hip_runtime.h>
#include <hip/hip_fp16.h>
#include <math.h>

// Problem constants (setup_inputs: data (16,256,1024) f32)
#define B_   16
#define V_   256
#define R_   1024
#define HR_  20      // G[1]+T[1] = 4+16
#define HV_  10      // G[0]+T[0] = 2+8
#define KTOP 8       // OS_N - K_ORDER = 32-24
#define CAN  16      // 2*T[0]

// ---------- packed-f16 primitives (2 independent selection problems/lane) ----------
__device__ __forceinline__ unsigned pkrtz(float a, float b) {
    unsigned d;
    asm("v_cvt_pkrtz_f16_f32 %0, %1, %2" : "=v"(d) : "v"(a), "v"(b));
    return d;
}
__device__ __forceinline__ unsigned hmax(unsigned a, unsigned b) {
    unsigned d; asm("v_pk_max_f16 %0, %1, %2" : "=v"(d) : "v"(a), "v"(b)); return d;
}
__device__ __forceinline__ unsigned hmin(unsigned a, unsigned b) {
    unsigned d; asm("v_pk_min_f16 %0, %1, %2" : "=v"(d) : "v"(a), "v"(b)); return d;
}
// compare-exchange, descending (a=max, b=min)
__device__ __forceinline__ void ceh(unsigned& a, unsigned& b) {
    unsigned mx, mn;
    asm("v_pk_max_f16 %0, %2, %3\n\t"
        "v_pk_min_f16 %1, %2, %3"
        : "=&v"(mx), "=v"(mn) : "v"(a), "v"(b));
    a = mx; b = mn;
}
__device__ __forceinline__ float lo16(unsigned u) {
    return __half2float(__ushort_as_half((unsigned short)(u & 0xffffu)));
}
__device__ __forceinline__ float hi16(unsigned u) {
    return __half2float(__ushort_as_half((unsigned short)(u >> 16)));
}

// Batcher odd-even mergesort, 8 elems, descending, 19 CE
__device__ __forceinline__ void sort8h(unsigned* c) {
    ceh(c[0],c[1]); ceh(c[2],c[3]); ceh(c[4],c[5]); ceh(c[6],c[7]);
    ceh(c[0],c[2]); ceh(c[1],c[3]); ceh(c[1],c[2]);
    ceh(c[4],c[6]); ceh(c[5],c[7]); ceh(c[5],c[6]);
    ceh(c[0],c[4]); ceh(c[2],c[6]); ceh(c[2],c[4]);
    ceh(c[1],c[5]); ceh(c[3],c[7]); ceh(c[3],c[5]);
    ceh(c[1],c[2]); ceh(c[3],c[4]); ceh(c[5],c[6]);
}
// Optimal 6-sorter, descending, 12 CE
__device__ __forceinline__ void sort6h(unsigned* c) {
    ceh(c[0],c[5]); ceh(c[1],c[3]); ceh(c[2],c[4]);
    ceh(c[1],c[2]); ceh(c[3],c[4]);
    ceh(c[0],c[3]); ceh(c[2],c[5]);
    ceh(c[0],c[1]); ceh(c[2],c[3]); ceh(c[4],c[5]);
    ceh(c[1],c[2]); ceh(c[3],c[4]);
}
// a,b sorted desc -> m = sorted top-8 multiset of a∪b (bitonic + 12-CE cleaner)
__device__ __forceinline__ void mt8h(const unsigned* a, const unsigned* b, unsigned* m) {
#pragma unroll
    for (int i = 0; i < 8; ++i) m[i] = hmax(a[i], b[7 - i]);
    ceh(m[0],m[4]); ceh(m[1],m[5]); ceh(m[2],m[6]); ceh(m[3],m[7]);
    ceh(m[0],m[2]); ceh(m[1],m[3]); ceh(m[4],m[6]); ceh(m[5],m[7]);
    ceh(m[0],m[1]); ceh(m[2],m[3]); ceh(m[4],m[5]); ceh(m[6],m[7]);
}

// Per-element finish vs sorted core top-8 m[] (extras padded with -inf at 6,7)
#define FINISHH(e0,e1,e2,e3,e4,e5, RES) {                                      \
    unsigned ex[6] = {e0, e1, e2, e3, e4, e5};                                 \
    sort6h(ex);                                                                \
    unsigned f2 = hmax(m[2], ex[5]);                                           \
    unsigned f3 = hmax(m[3], ex[4]);                                           \
    unsigned f4 = hmax(m[4], ex[3]);                                           \
    unsigned f5 = hmax(m[5], ex[2]);                                           \
    unsigned f6 = hmax(m[6], ex[1]);                                           \
    unsigned f7 = hmax(m[7], ex[0]);                                           \
    RES = hmin(hmin(hmin(m[1], f2), hmin(f3, f4)),                             \
               hmin(hmin(f5, f6), f7));                                        \
}

// ---------------- Stage 1: OS-CFAR along R (packed f16, direct-global) ---------
__global__ __launch_bounds__(256) void os_kernel(const float* __restrict__ data,
                                                 float* __restrict__ os,
                                                 float alpha) {
    const int t = threadIdx.x;
    const int row0 = blockIdx.x * 2;
    const int rs  = t >> 7;
    const int tid = t & 127;
    const int r0  = tid * 8;
    const float* __restrict__ src = data + (size_t)(row0 + rs) * R_;

    float x[48];
#pragma unroll
    for (int j = 0; j < 12; ++j) {
        const int idx = (r0 - HR_ + 4 * j) & (R_ - 1);
        *(float4*)&x[4 * j] = *(const float4*)&src[idx];
    }

    unsigned PL[20], PR[20];
#pragma unroll
    for (int k = 0; k < 20; ++k) PL[k] = pkrtz(x[k], x[k + 4]);
#pragma unroll
    for (int k = 0; k < 20; ++k) PR[k] = pkrtz(x[24 + k], x[28 + k]);

    unsigned c0[8] = {PL[3],PL[4],PL[5],PL[6],PL[7],PL[8],PL[9],PL[10]};
    unsigned c1[8] = {PL[11],PL[12],PL[13],PL[14],PL[15],PR[4],PR[5],PR[6]};
    unsigned c2[8] = {PR[7],PR[8],PR[9],PR[10],PR[11],PR[12],PR[13],PR[14]};
    sort8h(c0); sort8h(c1); sort8h(c2);
    unsigned m01[8], m[8];
    mt8h(c0, c1, m01);
    mt8h(m01, c2, m);
    unsigned t0 = PR[15], t1 = PR[16];
    ceh(t0, t1);
    m[6] = hmax(m[6], t1);
    m[7] = hmax(m[7], t0);
    ceh(m[0],m[4]); ceh(m[1],m[5]); ceh(m[2],m[6]); ceh(m[3],m[7]);
    ceh(m[0],m[2]); ceh(m[1],m[3]); ceh(m[4],m[6]); ceh(m[5],m[7]);
    ceh(m[0],m[1]); ceh(m[2],m[3]); ceh(m[4],m[5]); ceh(m[6],m[7]);

    unsigned res0, res1, res2, res3;
    FINISHH(PL[0],  PL[1],  PL[2],  PR[1],  PR[2],  PR[3],  res0);
    FINISHH(PL[1],  PL[2],  PL[16], PR[2],  PR[3],  PR[17], res1);
    FINISHH(PL[2],  PL[16], PL[17], PR[3],  PR[17], PR[18], res2);
    FINISHH(PL[16], PL[17], PL[18], PR[17], PR[18], PR[19], res3);

    float4 oA, oB;
    oA.x = alpha * lo16(res0); oB.x = alpha * hi16(res0);
    oA.y = alpha * lo16(res1); oB.y = alpha * hi16(res1);
    oA.z = alpha * lo16(res2); oB.z = alpha * hi16(res2);
    oA.w = alpha * lo16(res3); oB.w = alpha * hi16(res3);
    float* __restrict__ orow = os + (size_t)(row0 + rs) * R_ + r0;
    *(float4*)&orow[0] = oA;
    *(float4*)&orow[4] = oB;
}

// ---------------- Stage 2: CA along V (register sliding sums) ------------------
__device__ __forceinline__ float4 f4add(float4 a, float4 b) {
    return make_float4(a.x + b.x, a.y + b.y, a.z + b.z, a.w + b.w);
}
__device__ __forceinline__ float4 f4sub(float4 a, float4 b) {
    return make_float4(a.x - b.x, a.y - b.y, a.z - b.z, a.w - b.w);
}

__global__ __launch_bounds__(256) void ca_kernel(const float* __restrict__ os,
                                                 float* __restrict__ out) {
    const int swzb = ((blockIdx.x & 7) << 7) | (blockIdx.x >> 3);
    const int tid  = threadIdx.x;
    const int vq   = tid >> 6;
    const int rq   = tid & 63;
    const int rblk = swzb & 3;
    const int vblk = (swzb >> 2) & 15;
    const int b    = swzb >> 6;
    const int v0   = vblk * 16 + vq * 4;
    const int r    = rblk * 256 + rq * 4;
    const float* __restrict__ base = os + (size_t)b * V_ * R_;
    float* __restrict__ outb = out + (size_t)b * V_ * R_;

    float4 rowv[22];
#pragma unroll
    for (int d = 0; d <= 10; ++d)
        rowv[d] = *(const float4*)&base[((v0 + d - 10) & (V_ - 1)) * R_ + r];
#pragma unroll
    for (int d = 0; d <= 10; ++d)
        rowv[11 + d] = *(const float4*)&base[((v0 + d + 3) & (V_ - 1)) * R_ + r];

    float4 lo = rowv[0];
#pragma unroll
    for (int j = 1; j < 8; ++j) lo = f4add(lo, rowv[j]);
    float4 hi = rowv[11];
#pragma unroll
    for (int j = 12; j < 19; ++j) hi = f4add(hi, rowv[j]);

#pragma unroll
    for (int k = 0; k < 4; ++k) {
        float4 s = f4add(lo, hi);
        float4 o;
        o.x = s.x * (1.0f / CAN); o.y = s.y * (1.0f / CAN);
        o.z = s.z * (1.0f / CAN); o.w = s.w * (1.0f / CAN);
        *(float4*)&outb[(v0 + k) * R_ + r] = o;
        if (k < 3) {
            lo = f4add(f4sub(lo, rowv[k]),      rowv[k + 8]);
            hi = f4add(f4sub(hi, rowv[k + 11]), rowv[k + 19]);
        }
    }
}

// ---------------- Host: replicate reference alpha solve (float64) ----------------
static double lf_(double n) {
    n = n + 1.0;
    if (n < 9.0) {
        double f = 1.0;
        for (int i = 2; i <= (int)(n + 0.5); ++i) f *= (double)i;
        return log(f);
    }
    return 0.5 * (log(2.0 * M_PI) - log(n)) +
           n * (log(n + 1.0 / (12.0 * n - 0.1 / n)) - 1.0);
}

static double fun_(double k, double n, double t, double pfa) {
    double s = 0.0;
    for (int i = 0; i < (int)k; ++i) s += log(n - (double)i + t);
    return lf_(n) - lf_(n - k) - s - log(pfa);
}

static double solve_alpha_t_ref(void) {
    const double k = 24.0, n = 32.0, pfa = 1e-5;
    double t_max = 1e32, t_min = 1.0, m_n = 1.0;
    for (int it = 0; it < 10000; ++it) {
        double fmax_ = fun_(k, n, t_max, pfa);
        double fmin_ = fun_(k, n, t_min, pfa);
        m_n = t_max - fmax_ * (t_min - t_max) / (fmin_ - fmax_);
        double fm = fun_(k, n, m_n, pfa);
        if (fm == 0.0 || fabs(t_max - t_min) < 1e-4) return m_n;
        if (fmax_ * fm < 0.0)      t_min = m_n;
        else if (fmin_ * fm < 0.0) t_max = m_n;
        else break;
    }
    return m_n;
}

extern "C" void kernel_launch(void* const* d_in, const int* in_sizes, int n_in,
                              void* d_out, int out_size, void* d_ws, size_t ws_size,
                              hipStream_t stream) {
    const float* data = (const float*)d_in[0];
    float* out = (float*)d_out;
    float* os  = (float*)d_ws;                    // 16*256*1024*4 = 16.78 MB

    const float alpha = (float)sqrt(solve_alpha_t_ref());

    // ATTRIBUTION EXPERIMENT (round 11): launch each kernel TWICE.
    // Both are pure functions of their inputs -> bitwise-identical output,
    // graph-safe, same work every call. dur_new - 82.3 = (os + ca + gaps);
    // C_harness = 2*82.3 - dur_new. Decides whether the residual ~27 us is
    // kernel time (attack via fusion) or harness floor (declare roofline).
    os_kernel<<<B_ * V_ / 2, 256, 0, stream>>>(data, os, alpha);
    os_kernel<<<B_ * V_ / 2, 256, 0, stream>>>(data, os, alpha);

    const int blocks2 = B_ * 16 * 4;              // 1024
    ca_kernel<<<blocks2, 256, 0, stream>>>(os, out);
    ca_kernel<<<blocks2, 256, 0, stream>>>(os, out);
}

// Round 14
// 82.334 us; speedup vs baseline: 1.1915x; 1.1915x over previous
//
#include <hip/hip_runtime.h>
#include <math.h>

// Problem constants (setup_inputs: data (16,256,1024) f32)
#define B_   16
#define V_   256
#define R_   1024
#define HR_  20      // G[1]+T[1] = 4+16
#define HV_  10      // G[0]+T[0] = 2+8
#define KTOP 8       // OS_N - K_ORDER = 32-24
#define CAN  16      // 2*T[0]

// ---------- packed-f16 primitives via clang vector _Float16 (compiler-visible) ----
typedef _Float16 h2 __attribute__((ext_vector_type(2)));

// v_cvt_pkrtz as single-inst asm (no early-clobber -> no mov inflation).
__device__ __forceinline__ h2 pk2(float a, float b) {
    unsigned d;
    asm("v_cvt_pkrtz_f16_f32 %0, %1, %2" : "=v"(d) : "v"(a), "v"(b));
    return __builtin_bit_cast(h2, d);
}
// compare-exchange, descending (a=max, b=min) — elementwise builtins lower to
// v_pk_max_f16 / v_pk_min_f16 with full regalloc + CSE freedom.
__device__ __forceinline__ void ce2(h2& a, h2& b) {
    h2 mx = __builtin_elementwise_max(a, b);
    b = __builtin_elementwise_min(a, b);
    a = mx;
}
__device__ __forceinline__ h2 h2max(h2 a, h2 b) { return __builtin_elementwise_max(a, b); }
__device__ __forceinline__ h2 h2min(h2 a, h2 b) { return __builtin_elementwise_min(a, b); }

// Batcher odd-even mergesort, 8 elems, descending, 19 CE
__device__ __forceinline__ void sort8h(h2* c) {
    ce2(c[0],c[1]); ce2(c[2],c[3]); ce2(c[4],c[5]); ce2(c[6],c[7]);
    ce2(c[0],c[2]); ce2(c[1],c[3]); ce2(c[1],c[2]);
    ce2(c[4],c[6]); ce2(c[5],c[7]); ce2(c[5],c[6]);
    ce2(c[0],c[4]); ce2(c[2],c[6]); ce2(c[2],c[4]);
    ce2(c[1],c[5]); ce2(c[3],c[7]); ce2(c[3],c[5]);
    ce2(c[1],c[2]); ce2(c[3],c[4]); ce2(c[5],c[6]);
}
// Optimal 6-sorter, descending, 12 CE
__device__ __forceinline__ void sort6h(h2* c) {
    ce2(c[0],c[5]); ce2(c[1],c[3]); ce2(c[2],c[4]);
    ce2(c[1],c[2]); ce2(c[3],c[4]);
    ce2(c[0],c[3]); ce2(c[2],c[5]);
    ce2(c[0],c[1]); ce2(c[2],c[3]); ce2(c[4],c[5]);
    ce2(c[1],c[2]); ce2(c[3],c[4]);
}
// a,b sorted desc -> m = sorted top-8 multiset of a∪b (bitonic + 12-CE cleaner)
__device__ __forceinline__ void mt8h(const h2* a, const h2* b, h2* m) {
#pragma unroll
    for (int i = 0; i < 8; ++i) m[i] = h2max(a[i], b[7 - i]);
    ce2(m[0],m[4]); ce2(m[1],m[5]); ce2(m[2],m[6]); ce2(m[3],m[7]);
    ce2(m[0],m[2]); ce2(m[1],m[3]); ce2(m[4],m[6]); ce2(m[5],m[7]);
    ce2(m[0],m[1]); ce2(m[2],m[3]); ce2(m[4],m[5]); ce2(m[6],m[7]);
}

// Per-element finish vs sorted core top-8 m[] (extras padded with -inf at 6,7)
#define FINISHH(e0,e1,e2,e3,e4,e5, RES) {                                      \
    h2 ex[6] = {e0, e1, e2, e3, e4, e5};                                       \
    sort6h(ex);                                                                \
    h2 f2 = h2max(m[2], ex[5]);                                                \
    h2 f3 = h2max(m[3], ex[4]);                                                \
    h2 f4 = h2max(m[4], ex[3]);                                                \
    h2 f5 = h2max(m[5], ex[2]);                                                \
    h2 f6 = h2max(m[6], ex[1]);                                                \
    h2 f7 = h2max(m[7], ex[0]);                                                \
    RES = h2min(h2min(h2min(m[1], f2), h2min(f3, f4)),                         \
                h2min(h2min(f5, f6), f7));                                     \
}

// ---------------- Stage 1: OS-CFAR along R (packed f16, direct-global) ---------
// Block = 2 rows x 128 threads; thread handles 8 consecutive r as two packed
// 4-groups (lo/hi f16). x[k] = row[(r0-20+k) & 1023], k=0..47, loaded directly
// from global as 12 float4. Shared-core top-8 amortized over 4 packed elems.
__global__ __launch_bounds__(256) void os_kernel(const float* __restrict__ data,
                                                 float* __restrict__ os,
                                                 float alpha) {
    const int t = threadIdx.x;
    const int row0 = blockIdx.x * 2;
    const int rs  = t >> 7;
    const int tid = t & 127;
    const int r0  = tid * 8;
    const float* __restrict__ src = data + (size_t)(row0 + rs) * R_;

    float x[48];
#pragma unroll
    for (int j = 0; j < 12; ++j) {
        const int idx = (r0 - HR_ + 4 * j) & (R_ - 1);
        *(float4*)&x[4 * j] = *(const float4*)&src[idx];
    }

    h2 PL[20], PR[20];
#pragma unroll
    for (int k = 0; k < 20; ++k) PL[k] = pk2(x[k], x[k + 4]);
#pragma unroll
    for (int k = 0; k < 20; ++k) PR[k] = pk2(x[24 + k], x[28 + k]);

    // ---- core: sorted top-8 of the 26 shared samples (both groups packed) ----
    h2 c0[8] = {PL[3],PL[4],PL[5],PL[6],PL[7],PL[8],PL[9],PL[10]};
    h2 c1[8] = {PL[11],PL[12],PL[13],PL[14],PL[15],PR[4],PR[5],PR[6]};
    h2 c2[8] = {PR[7],PR[8],PR[9],PR[10],PR[11],PR[12],PR[13],PR[14]};
    sort8h(c0); sort8h(c1); sort8h(c2);
    h2 m01[8], m[8];
    mt8h(c0, c1, m01);
    mt8h(m01, c2, m);
    h2 t0 = PR[15], t1 = PR[16];
    ce2(t0, t1);
    m[6] = h2max(m[6], t1);
    m[7] = h2max(m[7], t0);
    ce2(m[0],m[4]); ce2(m[1],m[5]); ce2(m[2],m[6]); ce2(m[3],m[7]);
    ce2(m[0],m[2]); ce2(m[1],m[3]); ce2(m[4],m[6]); ce2(m[5],m[7]);
    ce2(m[0],m[1]); ce2(m[2],m[3]); ce2(m[4],m[5]); ce2(m[6],m[7]);

    // ---- per-element extras (6 private per element, both groups packed) ----
    h2 res0, res1, res2, res3;
    FINISHH(PL[0],  PL[1],  PL[2],  PR[1],  PR[2],  PR[3],  res0);
    FINISHH(PL[1],  PL[2],  PL[16], PR[2],  PR[3],  PR[17], res1);
    FINISHH(PL[2],  PL[16], PL[17], PR[3],  PR[17], PR[18], res2);
    FINISHH(PL[16], PL[17], PL[18], PR[17], PR[18], PR[19], res3);

    float4 oA, oB;
    oA.x = alpha * (float)res0[0]; oB.x = alpha * (float)res0[1];
    oA.y = alpha * (float)res1[0]; oB.y = alpha * (float)res1[1];
    oA.z = alpha * (float)res2[0]; oB.z = alpha * (float)res2[1];
    oA.w = alpha * (float)res3[0]; oB.w = alpha * (float)res3[1];
    float* __restrict__ orow = os + (size_t)(row0 + rs) * R_ + r0;
    *(float4*)&orow[0] = oA;
    *(float4*)&orow[4] = oB;
}

// ---------------- Stage 2: CA along V (register sliding sums) ------------------
__device__ __forceinline__ float4 f4add(float4 a, float4 b) {
    return make_float4(a.x + b.x, a.y + b.y, a.z + b.z, a.w + b.w);
}
__device__ __forceinline__ float4 f4sub(float4 a, float4 b) {
    return make_float4(a.x - b.x, a.y - b.y, a.z - b.z, a.w - b.w);
}

__global__ __launch_bounds__(256) void ca_kernel(const float* __restrict__ os,
                                                 float* __restrict__ out) {
    const int swzb = ((blockIdx.x & 7) << 7) | (blockIdx.x >> 3);
    const int tid  = threadIdx.x;
    const int vq   = tid >> 6;
    const int rq   = tid & 63;
    const int rblk = swzb & 3;
    const int vblk = (swzb >> 2) & 15;
    const int b    = swzb >> 6;
    const int v0   = vblk * 16 + vq * 4;
    const int r    = rblk * 256 + rq * 4;
    const float* __restrict__ base = os + (size_t)b * V_ * R_;
    float* __restrict__ outb = out + (size_t)b * V_ * R_;

    float4 rowv[22];
#pragma unroll
    for (int d = 0; d <= 10; ++d)
        rowv[d] = *(const float4*)&base[((v0 + d - 10) & (V_ - 1)) * R_ + r];
#pragma unroll
    for (int d = 0; d <= 10; ++d)
        rowv[11 + d] = *(const float4*)&base[((v0 + d + 3) & (V_ - 1)) * R_ + r];

    float4 lo = rowv[0];
#pragma unroll
    for (int j = 1; j < 8; ++j) lo = f4add(lo, rowv[j]);
    float4 hi = rowv[11];
#pragma unroll
    for (int j = 12; j < 19; ++j) hi = f4add(hi, rowv[j]);

#pragma unroll
    for (int k = 0; k < 4; ++k) {
        float4 s = f4add(lo, hi);
        float4 o;
        o.x = s.x * (1.0f / CAN); o.y = s.y * (1.0f / CAN);
        o.z = s.z * (1.0f / CAN); o.w = s.w * (1.0f / CAN);
        *(float4*)&outb[(v0 + k) * R_ + r] = o;
        if (k < 3) {
            lo = f4add(f4sub(lo, rowv[k]),      rowv[k + 8]);
            hi = f4add(f4sub(hi, rowv[k + 11]), rowv[k + 19]);
        }
    }
}

// ---------------- Host: replicate reference alpha solve (float64) ----------------
static double lf_(double n) {
    n = n + 1.0;
    if (n < 9.0) {
        double f = 1.0;
        for (int i = 2; i <= (int)(n + 0.5); ++i) f *= (double)i;
        return log(f);
    }
    return 0.5 * (log(2.0 * M_PI) - log(n)) +
           n * (log(n + 1.0 / (12.0 * n - 0.1 / n)) - 1.0);
}

static double fun_(double k, double n, double t, double pfa) {
    double s = 0.0;
    for (int i = 0; i < (int)k; ++i) s += log(n - (double)i + t);
    return lf_(n) - lf_(n - k) - s - log(pfa);
}

static double solve_alpha_t_ref(void) {
    const double k = 24.0, n = 32.0, pfa = 1e-5;
    double t_max = 1e32, t_min = 1.0, m_n = 1.0;
    for (int it = 0; it < 10000; ++it) {
        double fmax_ = fun_(k, n, t_max, pfa);
        double fmin_ = fun_(k, n, t_min, pfa);
        m_n = t_max - fmax_ * (t_min - t_max) / (fmin_ - fmax_);
        double fm = fun_(k, n, m_n, pfa);
        if (fm == 0.0 || fabs(t_max - t_min) < 1e-4) return m_n;
        if (fmax_ * fm < 0.0)      t_min = m_n;
        else if (fmin_ * fm < 0.0) t_max = m_n;
        else break;
    }
    return m_n;
}

extern "C" void kernel_launch(void* const* d_in, const int* in_sizes, int n_in,
                              void* d_out, int out_size, void* d_ws, size_t ws_size,
                              hipStream_t stream) {
    const float* data = (const float*)d_in[0];
    float* out = (float*)d_out;
    float* os  = (float*)d_ws;                    // 16*256*1024*4 = 16.78 MB

    const float alpha = (float)sqrt(solve_alpha_t_ref());

    os_kernel<<<B_ * V_ / 2, 256, 0, stream>>>(data, os, alpha);

    const int blocks2 = B_ * 16 * 4;              // 1024
    ca_kernel<<<blocks2, 256, 0, stream>>>(os, out);
}